// Round 3
// baseline (839.700 us; speedup 1.0000x reference)
//
#include <hip/hip_runtime.h>

#define NN 50000
#define EE 800000
#define FHID 128
#define NHEAD 4
#define NGRAPH 512
#define NCLS 10

typedef unsigned short u16;
typedef unsigned int u32;
typedef __attribute__((ext_vector_type(8))) short bf16x8;
typedef __attribute__((ext_vector_type(4))) float f32x4;

__device__ __forceinline__ float bf2f(u16 u){
    union { u32 i; float f; } v; v.i = ((u32)u) << 16; return v.f;
}
__device__ __forceinline__ u16 f2bf(float f){
    union { float f; u32 i; } v; v.f = f;
    u32 r = v.i + 0x7fffu + ((v.i >> 16) & 1u);
    return (u16)(r >> 16);
}
__device__ __forceinline__ float loadF(const void* p, int i, int isf32){
    return isf32 ? ((const float*)p)[i] : bf2f(((const u16*)p)[i]);
}

// ---------------- runtime input-dtype detection -------------------------------------
__global__ void detect_dtype(const u16* __restrict__ x, int* __restrict__ flag){
    __shared__ int cnt;
    if (threadIdx.x == 0) cnt = 0;
    __syncthreads();
    int ok = 0;
    for (int i = threadIdx.x; i < 1024; i += 256){
        u16 u = x[i];
        int e = (u >> 7) & 0xFF;
        if ((u & 0x7fff) == 0 || (e >= 0x70 && e <= 0x85)) ok++;
    }
    atomicAdd(&cnt, ok);
    __syncthreads();
    if (threadIdx.x == 0) flag[0] = (cnt < 900) ? 1 : 0;   // 1 = f32 inputs
}

// ---------------- convert x to internal bf16 ---------------------------------------
__global__ void convert_x(const void* __restrict__ x, u16* __restrict__ hX,
                          const int* __restrict__ flag, int n){
    int i = blockIdx.x*256 + threadIdx.x;
    int isf32 = flag[0];
    if (i < n) hX[i] = isf32 ? f2bf(((const float*)x)[i]) : ((const u16*)x)[i];
}

// ---------------- weight prep -------------------------------------------------------
__global__ void prep_weights(const void* __restrict__ w_feat, const void* __restrict__ b_feat,
                             const void* __restrict__ bn_feat_g, const void* __restrict__ bn_feat_b,
                             const void* __restrict__ w_gat, const void* __restrict__ bn_conv_g,
                             const void* __restrict__ bn_conv_b, const void* __restrict__ b_gat,
                             const int* __restrict__ flag,
                             u16* __restrict__ Wt, float* __restrict__ cvec,
                             float* __restrict__ biasv)
{
    int isf32 = flag[0];
    int L = blockIdx.x;       // 0 = feat layer, 1..3 = conv layers
    int n = threadIdx.x;      // output col 0..127
    const float rs = rsqrtf(1.0f + 1e-5f);
    int wof = (L > 0) ? (L-1)*FHID*FHID : 0;
    int bof = (L > 0) ? (L-1)*FHID : 0;
    float c = 0.0f;
    for (int k = 0; k < FHID; k++){
        float wv = (L == 0) ? loadF(w_feat, k*FHID + n, isf32)
                            : loadF(w_gat, wof + k*FHID + n, isf32);
        float bg = (L == 0) ? loadF(bn_feat_g, k, isf32) : loadF(bn_conv_g, bof + k, isf32);
        float bb = (L == 0) ? loadF(bn_feat_b, k, isf32) : loadF(bn_conv_b, bof + k, isf32);
        Wt[L*FHID*FHID + n*FHID + k] = f2bf(bg * rs * wv);
        c += bb * wv;
    }
    if (L == 0) c += loadF(b_feat, n, isf32);
    cvec[L*FHID + n] = c;
    if (L > 0) biasv[L*FHID + n] = loadF(b_gat, (L-1)*FHID + n, isf32);
}

// ---------------- head + attention params -> f32 workspace block --------------------
// hp layout: [0]=wfc 16384, [16384]=wcls 1280, [17664]=bnfcg, [17792]=bnfcb,
// [17920]=bfc, [18048]=bnhidg, [18176]=bnhidb, [18304]=bcls(10),
// [18320]=att_l 3*128, [18704]=att_r 3*128   (total 19088 floats)
__global__ void prep_head(const void* wfc, const void* bfc, const void* bnfg, const void* bnfb,
                          const void* bnhg, const void* bnhb, const void* wcls, const void* bcls,
                          const void* attl, const void* attr,
                          const int* __restrict__ flag, float* __restrict__ hp){
    int isf32 = flag[0];
    int t = threadIdx.x;
    for (int i = t; i < FHID*FHID; i += 256) hp[i] = loadF(wfc, i, isf32);
    for (int i = t; i < FHID*NCLS; i += 256) hp[16384 + i] = loadF(wcls, i, isf32);
    for (int i = t; i < 3*FHID; i += 256){
        hp[18320 + i] = loadF(attl, i, isf32);
        hp[18704 + i] = loadF(attr, i, isf32);
    }
    if (t < FHID){
        hp[17664 + t] = loadF(bnfg, t, isf32);
        hp[17792 + t] = loadF(bnfb, t, isf32);
        hp[17920 + t] = loadF(bfc,  t, isf32);
        hp[18048 + t] = loadF(bnhg, t, isf32);
        hp[18176 + t] = loadF(bnhb, t, isf32);
    }
    if (t < NCLS) hp[18304 + t] = loadF(bcls, t, isf32);
}

// ---------------- MFMA GEMM: out[N,128] = A[N,128] @ W' + c, optional relu ----------
__global__ __launch_bounds__(256) void gemm128(const u16* __restrict__ A,
                                               const u16* __restrict__ Wt,
                                               const float* __restrict__ cvec,
                                               u16* __restrict__ out, int relu)
{
    int wave = threadIdx.x >> 6;
    int lane = threadIdx.x & 63;
    int m = lane & 15, quad = lane >> 4;
    int rowbase = blockIdx.x * 64 + wave * 16;
    int arow = rowbase + m;
    bool av = arow < NN;
    f32x4 acc[8];
#pragma unroll
    for (int i = 0; i < 8; i++) acc[i] = (f32x4){0.f, 0.f, 0.f, 0.f};
#pragma unroll
    for (int t = 0; t < 4; t++){
        bf16x8 afrag = {0,0,0,0,0,0,0,0};
        if (av) afrag = *(const bf16x8*)(A + (size_t)arow*FHID + t*32 + quad*8);
#pragma unroll
        for (int ct = 0; ct < 8; ct++){
            int col = ct*16 + m;
            bf16x8 bfrag = *(const bf16x8*)(Wt + col*FHID + t*32 + quad*8);
            acc[ct] = __builtin_amdgcn_mfma_f32_16x16x32_bf16(afrag, bfrag, acc[ct], 0, 0, 0);
        }
    }
#pragma unroll
    for (int ct = 0; ct < 8; ct++){
        int col = ct*16 + m;
        float cb = cvec[col];
#pragma unroll
        for (int r = 0; r < 4; r++){
            int row = rowbase + quad*4 + r;
            if (row < NN){
                float v = acc[ct][r] + cb;
                if (relu) v = fmaxf(v, 0.f);
                out[(size_t)row*FHID + col] = f2bf(v);
            }
        }
    }
}

// ---------------- per-node, per-head attention scalars (att params f32 in hp) -------
__global__ void node_alpha(const u16* __restrict__ hh, const float* __restrict__ attl,
                           const float* __restrict__ attr,
                           float* __restrict__ al, float* __restrict__ ar)
{
    int idx = blockIdx.x*blockDim.x + threadIdx.x;   // node*4 + head
    if (idx >= NN*NHEAD) return;
    int head = idx & 3;
    const u16* base = hh + (size_t)(idx >> 2)*FHID + head*32;
    float sl = 0.f, sr = 0.f;
    for (int c = 0; c < 32; c++){
        float f = bf2f(base[c]);
        sl += f * attl[head*32 + c];
        sr += f * attr[head*32 + c];
    }
    al[idx] = sl; ar[idx] = sr;
}

// ---------------- CSR build ---------------------------------------------------------
__global__ void zero_i32(int* p, int n){ int i = blockIdx.x*256 + threadIdx.x; if (i < n) p[i] = 0; }
__global__ void zero_f32(float* p, int n){ int i = blockIdx.x*256 + threadIdx.x; if (i < n) p[i] = 0.f; }

__global__ void count_deg(const int* __restrict__ dst, int* __restrict__ deg){
    int e = blockIdx.x*256 + threadIdx.x;
    if (e < EE){
        u32 d = (u32)dst[e];
        if (d < NN) atomicAdd(&deg[d], 1);
    }
}
__global__ void scan_block_sum(const int* __restrict__ deg, int* __restrict__ bsum, int n){
    __shared__ int sm[256];
    int i = blockIdx.x*256 + threadIdx.x;
    sm[threadIdx.x] = (i < n) ? deg[i] : 0;
    __syncthreads();
    for (int off = 128; off > 0; off >>= 1){
        if (threadIdx.x < off) sm[threadIdx.x] += sm[threadIdx.x + off];
        __syncthreads();
    }
    if (threadIdx.x == 0) bsum[blockIdx.x] = sm[0];
}
__global__ void scan_bsum(int* bsum, int nb, int* total_out){
    if (threadIdx.x == 0 && blockIdx.x == 0){
        int run = 0;
        for (int i = 0; i < nb; i++){ int t = bsum[i]; bsum[i] = run; run += t; }
        *total_out = run;
    }
}
__global__ void scan_final(const int* __restrict__ deg, const int* __restrict__ bsum,
                           int* __restrict__ rowstart, int n){
    __shared__ int sm[256];
    int i = blockIdx.x*256 + threadIdx.x;
    int v = (i < n) ? deg[i] : 0;
    sm[threadIdx.x] = v;
    __syncthreads();
    for (int off = 1; off < 256; off <<= 1){
        int x = (threadIdx.x >= off) ? sm[threadIdx.x - off] : 0;
        __syncthreads();
        sm[threadIdx.x] += x;
        __syncthreads();
    }
    if (i < n) rowstart[i] = bsum[blockIdx.x] + sm[threadIdx.x] - v;   // exclusive
}
__global__ void copy_i32(const int* a, int* b, int n){
    int i = blockIdx.x*256 + threadIdx.x; if (i < n) b[i] = a[i];
}
__global__ void fill_csr(const int* __restrict__ srcp, const int* __restrict__ dstp,
                         int* __restrict__ cursor, int* __restrict__ colb){
    int e = blockIdx.x*256 + threadIdx.x;
    if (e < EE){
        u32 d = (u32)dstp[e];
        if (d < NN){
            u32 pos = (u32)atomicAdd(&cursor[d], 1);
            if (pos < EE) colb[pos] = srcp[e];
        }
    }
}

// ---------------- SuperGAT conv: one wave per dst node, online softmax --------------
__device__ __forceinline__ float headsum(float v){
    v += __shfl_xor(v, 1, 64);
    v += __shfl_xor(v, 2, 64);
    v += __shfl_xor(v, 4, 64);
    v += __shfl_xor(v, 8, 64);
    return v;
}

__global__ __launch_bounds__(256) void supergat_conv(const u16* __restrict__ hh,
        const float* __restrict__ al, const float* __restrict__ ar,
        const int* __restrict__ rowstart, const int* __restrict__ colbuf,
        const float* __restrict__ bias, u16* __restrict__ hout)
{
    int gwid = (blockIdx.x*256 + threadIdx.x) >> 6;   // node id
    if (gwid >= NN) return;
    int lane = threadIdx.x & 63;
    int head = lane >> 4;
    u32 hd = *(const u32*)(hh + (size_t)gwid*FHID + 2*lane);
    float hd0 = bf2f((u16)(hd & 0xffff));
    float hd1 = bf2f((u16)(hd >> 16));
    float arn = ar[gwid*NHEAD + head];
    float aln = al[gwid*NHEAD + head];

    float logit = headsum(hd0*hd0 + hd1*hd1);
    float a = (aln + arn) * (1.0f / (1.0f + __expf(-logit)));
    a = (a > 0.0f) ? a : 0.2f*a;
    float m = a, s = 1.0f, o0 = hd0, o1 = hd1;

    int e0 = rowstart[gwid], e1 = rowstart[gwid + 1];
    if (e0 < 0) e0 = 0;
    if (e1 > EE) e1 = EE;
    for (int e = e0; e < e1; e++){
        int src = colbuf[e];
        if ((u32)src >= NN) src = gwid;
        u32 hs = *(const u32*)(hh + (size_t)src*FHID + 2*lane);
        float hs0 = bf2f((u16)(hs & 0xffff));
        float hs1 = bf2f((u16)(hs >> 16));
        float lg = headsum(hd0*hs0 + hd1*hs1);
        float a2 = (al[src*NHEAD + head] + arn) * (1.0f / (1.0f + __expf(-lg)));
        a2 = (a2 > 0.0f) ? a2 : 0.2f*a2;
        float mn = fmaxf(m, a2);
        float f = __expf(m - mn);
        float p = __expf(a2 - mn);
        s = s*f + p;
        o0 = o0*f + p*hs0;
        o1 = o1*f + p*hs1;
        m = mn;
    }
    float inv = 1.0f / (s + 1e-16f);
    float v0 = fmaxf(o0*inv + bias[2*lane],     0.f);
    float v1 = fmaxf(o1*inv + bias[2*lane + 1], 0.f);
    *(u32*)(hout + (size_t)gwid*FHID + 2*lane) = ((u32)f2bf(v1) << 16) | f2bf(v0);
}

// ---------------- global add pool (batch sorted) ------------------------------------
__global__ void pool_kernel(const u16* __restrict__ h, const int* __restrict__ batch,
                            float* __restrict__ g)
{
    int t = threadIdx.x;
    int start = blockIdx.x * 256;
    if (start >= NN) return;
    int end = min(start + 256, NN);
    int curb = batch[start] & (NGRAPH - 1);
    float acc = 0.f;
    for (int node = start; node < end; node++){
        int b = batch[node] & (NGRAPH - 1);
        if (b != curb){ atomicAdd(&g[curb*FHID + t], acc); acc = 0.f; curb = b; }
        acc += bf2f(h[(size_t)node*FHID + t]);
    }
    atomicAdd(&g[curb*FHID + t], acc);
}

// ---------------- head: BN -> fc -> relu -> BN -> cls -> log_softmax ----------------
__global__ void head_kernel(const float* __restrict__ g, const float* __restrict__ hp,
                            const int* __restrict__ flag, void* __restrict__ out)
{
    __shared__ float gb[FHID];
    __shared__ float g2[FHID];
    __shared__ float lg[16];
    int gi = blockIdx.x, t = threadIdx.x;
    int isf32 = flag[0];
    const float rs = rsqrtf(1.0f + 1e-5f);
    gb[t] = g[gi*FHID + t] * (hp[17664 + t] * rs) + hp[17792 + t];
    __syncthreads();
    float acc = hp[17920 + t];
    for (int k = 0; k < FHID; k++) acc += gb[k] * hp[k*FHID + t];
    acc = fmaxf(acc, 0.f);
    g2[t] = acc * (hp[18048 + t] * rs) + hp[18176 + t];
    __syncthreads();
    if (t < NCLS){
        float l = hp[18304 + t];
        for (int k = 0; k < FHID; k++) l += g2[k] * hp[16384 + k*NCLS + t];
        lg[t] = l;
    }
    __syncthreads();
    if (t == 0){
        float mx = lg[0];
        for (int j = 1; j < NCLS; j++) mx = fmaxf(mx, lg[j]);
        float se = 0.f;
        for (int j = 0; j < NCLS; j++) se += __expf(lg[j] - mx);
        float lse = logf(se) + mx;
        if (isf32){
            float* o = (float*)out;
            for (int j = 0; j < NCLS; j++) o[gi*NCLS + j] = lg[j] - lse;
            if (gi == 0) o[NGRAPH*NCLS] = 0.f;
        } else {
            u16* o = (u16*)out;
            for (int j = 0; j < NCLS; j++) o[gi*NCLS + j] = f2bf(lg[j] - lse);
            if (gi == 0) o[NGRAPH*NCLS] = 0;
        }
    }
}

extern "C" void kernel_launch(void* const* d_in, const int* in_sizes, int n_in,
                              void* d_out, int out_size, void* d_ws, size_t ws_size,
                              hipStream_t stream)
{
    (void)in_sizes; (void)n_in; (void)out_size;
    const void* x         = d_in[0];
    const int* edge       = (const int*)d_in[1];
    const int* batch      = (const int*)d_in[2];

    char* ws = (char*)d_ws;
    size_t off = 0;
    auto alloc = [&](size_t bytes) -> char* {
        char* p = ws + off; off += (bytes + 255) & ~(size_t)255; return p;
    };
    int*   dflag   = (int*)  alloc(256);
    u16*   WtAll   = (u16*)  alloc((size_t)4*FHID*FHID*2);
    float* cvecAll = (float*)alloc((size_t)4*FHID*4);
    float* biasv   = (float*)alloc((size_t)4*FHID*4);
    float* headp   = (float*)alloc((size_t)19088*4);
    float* al      = (float*)alloc((size_t)NN*NHEAD*4);
    float* ar      = (float*)alloc((size_t)NN*NHEAD*4);
    int*   deg     = (int*)  alloc((size_t)NN*4);
    int*   rowst   = (int*)  alloc((size_t)(NN+1)*4);
    int*   cursor  = (int*)  alloc((size_t)NN*4);
    int*   bsum    = (int*)  alloc((size_t)256*4);
    float* g       = (float*)alloc((size_t)NGRAPH*FHID*4);
    int*   colbuf  = (int*)  alloc((size_t)EE*4);
    u16*   hA      = (u16*)  alloc((size_t)NN*FHID*2);
    u16* hX;   // doubles as hB (hX dead after first gemm consumes it)
    if (off + (size_t)NN*FHID*2 <= ws_size) hX = (u16*)alloc((size_t)NN*FHID*2);
    else                                    hX = (u16*)d_in[0];
    u16* hB = hX;

    const int* srcp = edge;
    const int* dstp = edge + EE;
    const int NB_N = (NN + 255)/256;
    const int NB_E = (EE + 255)/256;
    const int NB_X = (NN*FHID + 255)/256;

    detect_dtype<<<1, 256, 0, stream>>>((const u16*)x, dflag);
    prep_weights<<<4, 128, 0, stream>>>(d_in[5], d_in[6], d_in[3], d_in[4],
                                        d_in[9], d_in[7], d_in[8], d_in[12],
                                        dflag, WtAll, cvecAll, biasv);
    prep_head<<<1, 256, 0, stream>>>(d_in[15], d_in[16], d_in[13], d_in[14],
                                     d_in[17], d_in[18], d_in[19], d_in[20],
                                     d_in[10], d_in[11], dflag, headp);
    convert_x<<<NB_X, 256, 0, stream>>>(x, hX, dflag, NN*FHID);

    zero_i32<<<NB_N, 256, 0, stream>>>(deg, NN);
    zero_i32<<<NB_E, 256, 0, stream>>>(colbuf, EE);
    count_deg<<<NB_E, 256, 0, stream>>>(dstp, deg);
    scan_block_sum<<<NB_N, 256, 0, stream>>>(deg, bsum, NN);
    scan_bsum<<<1, 64, 0, stream>>>(bsum, NB_N, rowst + NN);
    scan_final<<<NB_N, 256, 0, stream>>>(deg, bsum, rowst, NN);
    copy_i32<<<NB_N, 256, 0, stream>>>(rowst, cursor, NN);
    fill_csr<<<NB_E, 256, 0, stream>>>(srcp, dstp, cursor, colbuf);

    gemm128<<<(NN + 63)/64, 256, 0, stream>>>(hX, WtAll, cvecAll, hA, 1);

    for (int i = 0; i < 3; i++){
        gemm128<<<(NN + 63)/64, 256, 0, stream>>>(hA, WtAll + (i+1)*FHID*FHID,
                                                  cvecAll + (i+1)*FHID, hB, 0);
        node_alpha<<<(NN*NHEAD + 255)/256, 256, 0, stream>>>(hB, headp + 18320 + i*FHID,
                                                             headp + 18704 + i*FHID, al, ar);
        supergat_conv<<<(NN + 3)/4, 256, 0, stream>>>(hB, al, ar, rowst, colbuf,
                                                      biasv + (i+1)*FHID, hA);
    }

    zero_f32<<<(NGRAPH*FHID + 255)/256, 256, 0, stream>>>(g, NGRAPH*FHID);
    pool_kernel<<<NB_N, 128, 0, stream>>>(hA, batch, g);
    head_kernel<<<NGRAPH, 128, 0, stream>>>(g, headp, dflag, d_out);
}

// Round 4
// 593.347 us; speedup vs baseline: 1.4152x; 1.4152x over previous
//
#include <hip/hip_runtime.h>

#define NN 50000
#define EE 800000
#define FHID 128
#define NHEAD 4
#define NGRAPH 512
#define NCLS 10

typedef unsigned short u16;
typedef unsigned int u32;
typedef __attribute__((ext_vector_type(8))) short bf16x8;
typedef __attribute__((ext_vector_type(4))) float f32x4;

__device__ __forceinline__ float bf2f(u16 u){
    union { u32 i; float f; } v; v.i = ((u32)u) << 16; return v.f;
}
__device__ __forceinline__ float bflo(u32 u){
    union { u32 i; float f; } v; v.i = u << 16; return v.f;
}
__device__ __forceinline__ float bfhi(u32 u){
    union { u32 i; float f; } v; v.i = u & 0xffff0000u; return v.f;
}
__device__ __forceinline__ u16 f2bf(float f){
    union { float f; u32 i; } v; v.f = f;
    u32 r = v.i + 0x7fffu + ((v.i >> 16) & 1u);
    return (u16)(r >> 16);
}
__device__ __forceinline__ u32 pack2(float a, float b){
    return ((u32)f2bf(b) << 16) | f2bf(a);
}
__device__ __forceinline__ float loadF(const void* p, int i, int isf32){
    return isf32 ? ((const float*)p)[i] : bf2f(((const u16*)p)[i]);
}
__device__ __forceinline__ void unpk8(uint4 v, float* f){
    f[0]=bflo(v.x); f[1]=bfhi(v.x);
    f[2]=bflo(v.y); f[3]=bfhi(v.y);
    f[4]=bflo(v.z); f[5]=bfhi(v.z);
    f[6]=bflo(v.w); f[7]=bfhi(v.w);
}

// ---------------- runtime input-dtype detection -------------------------------------
__global__ void detect_dtype(const u16* __restrict__ x, int* __restrict__ flag){
    __shared__ int cnt;
    if (threadIdx.x == 0) cnt = 0;
    __syncthreads();
    int ok = 0;
    for (int i = threadIdx.x; i < 1024; i += 256){
        u16 u = x[i];
        int e = (u >> 7) & 0xFF;
        if ((u & 0x7fff) == 0 || (e >= 0x70 && e <= 0x85)) ok++;
    }
    atomicAdd(&cnt, ok);
    __syncthreads();
    if (threadIdx.x == 0) flag[0] = (cnt < 900) ? 1 : 0;   // 1 = f32 inputs
}

// ---------------- convert x to internal bf16 ---------------------------------------
__global__ void convert_x(const void* __restrict__ x, u16* __restrict__ hX,
                          const int* __restrict__ flag, int n){
    int i = blockIdx.x*256 + threadIdx.x;
    int isf32 = flag[0];
    if (i < n) hX[i] = isf32 ? f2bf(((const float*)x)[i]) : ((const u16*)x)[i];
}

// ---------------- weight prep -------------------------------------------------------
__global__ void prep_weights(const void* __restrict__ w_feat, const void* __restrict__ b_feat,
                             const void* __restrict__ bn_feat_g, const void* __restrict__ bn_feat_b,
                             const void* __restrict__ w_gat, const void* __restrict__ bn_conv_g,
                             const void* __restrict__ bn_conv_b, const void* __restrict__ b_gat,
                             const int* __restrict__ flag,
                             u16* __restrict__ Wt, float* __restrict__ cvec,
                             float* __restrict__ biasv)
{
    int isf32 = flag[0];
    int L = blockIdx.x;       // 0 = feat layer, 1..3 = conv layers
    int n = threadIdx.x;      // output col 0..127
    const float rs = rsqrtf(1.0f + 1e-5f);
    int wof = (L > 0) ? (L-1)*FHID*FHID : 0;
    int bof = (L > 0) ? (L-1)*FHID : 0;
    float c = 0.0f;
    for (int k = 0; k < FHID; k++){
        float wv = (L == 0) ? loadF(w_feat, k*FHID + n, isf32)
                            : loadF(w_gat, wof + k*FHID + n, isf32);
        float bg = (L == 0) ? loadF(bn_feat_g, k, isf32) : loadF(bn_conv_g, bof + k, isf32);
        float bb = (L == 0) ? loadF(bn_feat_b, k, isf32) : loadF(bn_conv_b, bof + k, isf32);
        Wt[L*FHID*FHID + n*FHID + k] = f2bf(bg * rs * wv);
        c += bb * wv;
    }
    if (L == 0) c += loadF(b_feat, n, isf32);
    cvec[L*FHID + n] = c;
    if (L > 0) biasv[L*FHID + n] = loadF(b_gat, (L-1)*FHID + n, isf32);
}

// ---------------- head + attention params -> f32 workspace block --------------------
// hp layout: [0]=wfc 16384, [16384]=wcls 1280, [17664]=bnfcg, [17792]=bnfcb,
// [17920]=bfc, [18048]=bnhidg, [18176]=bnhidb, [18304]=bcls(10),
// [18320]=att_l 3*128, [18704]=att_r 3*128
__global__ void prep_head(const void* wfc, const void* bfc, const void* bnfg, const void* bnfb,
                          const void* bnhg, const void* bnhb, const void* wcls, const void* bcls,
                          const void* attl, const void* attr,
                          const int* __restrict__ flag, float* __restrict__ hp){
    int isf32 = flag[0];
    int t = threadIdx.x;
    for (int i = t; i < FHID*FHID; i += 256) hp[i] = loadF(wfc, i, isf32);
    for (int i = t; i < FHID*NCLS; i += 256) hp[16384 + i] = loadF(wcls, i, isf32);
    for (int i = t; i < 3*FHID; i += 256){
        hp[18320 + i] = loadF(attl, i, isf32);
        hp[18704 + i] = loadF(attr, i, isf32);
    }
    if (t < FHID){
        hp[17664 + t] = loadF(bnfg, t, isf32);
        hp[17792 + t] = loadF(bnfb, t, isf32);
        hp[17920 + t] = loadF(bfc,  t, isf32);
        hp[18048 + t] = loadF(bnhg, t, isf32);
        hp[18176 + t] = loadF(bnhb, t, isf32);
    }
    if (t < NCLS) hp[18304 + t] = loadF(bcls, t, isf32);
}

// ---------------- MFMA GEMM: out[N,128] = A[N,128] @ W' + c, optional relu ----------
__global__ __launch_bounds__(256) void gemm128(const u16* __restrict__ A,
                                               const u16* __restrict__ Wt,
                                               const float* __restrict__ cvec,
                                               u16* __restrict__ out, int relu)
{
    int wave = threadIdx.x >> 6;
    int lane = threadIdx.x & 63;
    int m = lane & 15, quad = lane >> 4;
    int rowbase = blockIdx.x * 64 + wave * 16;
    int arow = rowbase + m;
    bool av = arow < NN;
    f32x4 acc[8];
#pragma unroll
    for (int i = 0; i < 8; i++) acc[i] = (f32x4){0.f, 0.f, 0.f, 0.f};
#pragma unroll
    for (int t = 0; t < 4; t++){
        bf16x8 afrag = {0,0,0,0,0,0,0,0};
        if (av) afrag = *(const bf16x8*)(A + (size_t)arow*FHID + t*32 + quad*8);
#pragma unroll
        for (int ct = 0; ct < 8; ct++){
            int col = ct*16 + m;
            bf16x8 bfrag = *(const bf16x8*)(Wt + col*FHID + t*32 + quad*8);
            acc[ct] = __builtin_amdgcn_mfma_f32_16x16x32_bf16(afrag, bfrag, acc[ct], 0, 0, 0);
        }
    }
#pragma unroll
    for (int ct = 0; ct < 8; ct++){
        int col = ct*16 + m;
        float cb = cvec[col];
#pragma unroll
        for (int r = 0; r < 4; r++){
            int row = rowbase + quad*4 + r;
            if (row < NN){
                float v = acc[ct][r] + cb;
                if (relu) v = fmaxf(v, 0.f);
                out[(size_t)row*FHID + col] = f2bf(v);
            }
        }
    }
}

// ---------------- per-node, per-head attention scalars (vectorized) -----------------
__global__ void node_alpha(const u16* __restrict__ hh, const float* __restrict__ attl,
                           const float* __restrict__ attr,
                           float* __restrict__ al, float* __restrict__ ar)
{
    int idx = blockIdx.x*blockDim.x + threadIdx.x;   // node*4 + head
    if (idx >= NN*NHEAD) return;
    int head = idx & 3;
    const u16* base = hh + (size_t)(idx >> 2)*FHID + head*32;
    float sl = 0.f, sr = 0.f;
#pragma unroll
    for (int v = 0; v < 4; v++){
        uint4 u = *(const uint4*)(base + v*8);
        float f[8]; unpk8(u, f);
#pragma unroll
        for (int j = 0; j < 8; j++){
            int c = head*32 + v*8 + j;
            sl += f[j] * attl[c];
            sr += f[j] * attr[c];
        }
    }
    al[idx] = sl; ar[idx] = sr;
}

// ---------------- CSR build ---------------------------------------------------------
__global__ void zero_i32(int* p, int n){ int i = blockIdx.x*256 + threadIdx.x; if (i < n) p[i] = 0; }

__global__ void count_deg(const int* __restrict__ dst, int* __restrict__ deg){
    int e = blockIdx.x*256 + threadIdx.x;
    if (e < EE){
        u32 d = (u32)dst[e];
        if (d < NN) atomicAdd(&deg[d], 1);
    }
}
__global__ void scan_block_sum(const int* __restrict__ deg, int* __restrict__ bsum, int n){
    __shared__ int sm[256];
    int i = blockIdx.x*256 + threadIdx.x;
    sm[threadIdx.x] = (i < n) ? deg[i] : 0;
    __syncthreads();
    for (int off = 128; off > 0; off >>= 1){
        if (threadIdx.x < off) sm[threadIdx.x] += sm[threadIdx.x + off];
        __syncthreads();
    }
    if (threadIdx.x == 0) bsum[blockIdx.x] = sm[0];
}
// parallel exclusive scan of block sums (nb <= 256), one block of 256 threads
__global__ void scan_bsum_par(int* bsum, int nb, int* total_out){
    __shared__ int sm[256];
    int t = threadIdx.x;
    int v = (t < nb) ? bsum[t] : 0;
    sm[t] = v;
    __syncthreads();
    for (int off = 1; off < 256; off <<= 1){
        int x = (t >= off) ? sm[t - off] : 0;
        __syncthreads();
        sm[t] += x;
        __syncthreads();
    }
    if (t < nb) bsum[t] = sm[t] - v;          // exclusive
    if (t == 255) *total_out = sm[255];       // grand total
}
__global__ void scan_final(const int* __restrict__ deg, const int* __restrict__ bsum,
                           int* __restrict__ rowstart, int n){
    __shared__ int sm[256];
    int i = blockIdx.x*256 + threadIdx.x;
    int v = (i < n) ? deg[i] : 0;
    sm[threadIdx.x] = v;
    __syncthreads();
    for (int off = 1; off < 256; off <<= 1){
        int x = (threadIdx.x >= off) ? sm[threadIdx.x - off] : 0;
        __syncthreads();
        sm[threadIdx.x] += x;
        __syncthreads();
    }
    if (i < n) rowstart[i] = bsum[blockIdx.x] + sm[threadIdx.x] - v;   // exclusive
}
__global__ void copy_i32(const int* a, int* b, int n){
    int i = blockIdx.x*256 + threadIdx.x; if (i < n) b[i] = a[i];
}
__global__ void fill_csr(const int* __restrict__ srcp, const int* __restrict__ dstp,
                         int* __restrict__ cursor, int* __restrict__ colb){
    int e = blockIdx.x*256 + threadIdx.x;
    if (e < EE){
        u32 d = (u32)dstp[e];
        if (d < NN){
            u32 pos = (u32)atomicAdd(&cursor[d], 1);
            if (pos < EE) colb[pos] = srcp[e];
        }
    }
}

// ---------------- SuperGAT conv v2: 4 nodes/wave, 16 lanes/node, 8 ch/lane ----------
// lane = group*16 + head*4 + q ; channels = head*32 + q*8 .. +8
__global__ __launch_bounds__(256) void supergat_conv(const u16* __restrict__ hh,
        const float* __restrict__ al, const float* __restrict__ ar,
        const int* __restrict__ rowstart, const int* __restrict__ colbuf,
        const float* __restrict__ bias, u16* __restrict__ hout)
{
    int wid  = (blockIdx.x*256 + threadIdx.x) >> 6;   // wave id
    int lane = threadIdx.x & 63;
    int group = lane >> 4;
    int gl    = lane & 15;
    int head  = gl >> 2;
    int q     = gl & 3;
    int node  = wid*4 + group;
    bool valid = node < NN;
    int chbase = head*32 + q*8;
    int snode = valid ? node : 0;

    uint4 hdv = *(const uint4*)(hh + (size_t)snode*FHID + chbase);
    float hd[8]; unpk8(hdv, hd);
    float arn = ar[snode*NHEAD + head];
    float aln = al[snode*NHEAD + head];

    // self loop
    float d = hd[0]*hd[0]+hd[1]*hd[1]+hd[2]*hd[2]+hd[3]*hd[3]
            + hd[4]*hd[4]+hd[5]*hd[5]+hd[6]*hd[6]+hd[7]*hd[7];
    d += __shfl_xor(d, 1, 64);
    d += __shfl_xor(d, 2, 64);
    float a = (aln + arn) * (1.0f / (1.0f + __expf(-d)));
    a = (a > 0.0f) ? a : 0.2f*a;
    float m = a, s = 1.0f;
    float o[8];
#pragma unroll
    for (int i = 0; i < 8; i++) o[i] = hd[i];

    int e0 = valid ? rowstart[node]     : 0;
    int e1 = valid ? rowstart[node + 1] : 0;
    if (e0 < 0) e0 = 0;
    if (e1 > EE) e1 = EE;

    // software-pipelined edge loop
    int   src_nx = 0;
    uint4 hsv_nx = (uint4){0,0,0,0};
    float alf_nx = 0.f;
    if (e0 < e1){
        src_nx = colbuf[e0];
        if ((u32)src_nx >= NN) src_nx = 0;
        hsv_nx = *(const uint4*)(hh + (size_t)src_nx*FHID + chbase);
        alf_nx = al[src_nx*NHEAD + head];
    }
    for (int e = e0; e < e1; e++){
        uint4 hsv = hsv_nx;
        float alf = alf_nx;
        if (e + 1 < e1){
            int s2 = colbuf[e + 1];
            if ((u32)s2 >= NN) s2 = 0;
            src_nx = s2;
            hsv_nx = *(const uint4*)(hh + (size_t)s2*FHID + chbase);
            alf_nx = al[s2*NHEAD + head];
        }
        float hs[8]; unpk8(hsv, hs);
        float lg = hd[0]*hs[0]+hd[1]*hs[1]+hd[2]*hs[2]+hd[3]*hs[3]
                 + hd[4]*hs[4]+hd[5]*hs[5]+hd[6]*hs[6]+hd[7]*hs[7];
        lg += __shfl_xor(lg, 1, 64);
        lg += __shfl_xor(lg, 2, 64);
        float a2 = (alf + arn) * (1.0f / (1.0f + __expf(-lg)));
        a2 = (a2 > 0.0f) ? a2 : 0.2f*a2;
        float mn = fmaxf(m, a2);
        float f = __expf(m - mn);
        float p = __expf(a2 - mn);
        s = s*f + p;
#pragma unroll
        for (int i = 0; i < 8; i++) o[i] = o[i]*f + p*hs[i];
        m = mn;
    }

    if (valid){
        float inv = 1.0f / (s + 1e-16f);
        uint4 w;
        float v0, v1;
        v0 = fmaxf(o[0]*inv + bias[chbase+0], 0.f);
        v1 = fmaxf(o[1]*inv + bias[chbase+1], 0.f);
        w.x = pack2(v0, v1);
        v0 = fmaxf(o[2]*inv + bias[chbase+2], 0.f);
        v1 = fmaxf(o[3]*inv + bias[chbase+3], 0.f);
        w.y = pack2(v0, v1);
        v0 = fmaxf(o[4]*inv + bias[chbase+4], 0.f);
        v1 = fmaxf(o[5]*inv + bias[chbase+5], 0.f);
        w.z = pack2(v0, v1);
        v0 = fmaxf(o[6]*inv + bias[chbase+6], 0.f);
        v1 = fmaxf(o[7]*inv + bias[chbase+7], 0.f);
        w.w = pack2(v0, v1);
        *(uint4*)(hout + (size_t)node*FHID + chbase) = w;
    }
}

// ---------------- global add pool: one block per graph, binary search ---------------
__global__ void pool_kernel(const u16* __restrict__ h, const int* __restrict__ batch,
                            float* __restrict__ g)
{
    __shared__ int bounds[2];
    int b = blockIdx.x, t = threadIdx.x;
    if (t < 2){
        int target = b + t;
        int lo = 0, hi = NN;
        while (lo < hi){
            int mid = (lo + hi) >> 1;
            if (batch[mid] < target) lo = mid + 1; else hi = mid;
        }
        bounds[t] = lo;
    }
    __syncthreads();
    float acc = 0.f;
    for (int node = bounds[0]; node < bounds[1]; node++)
        acc += bf2f(h[(size_t)node*FHID + t]);
    g[b*FHID + t] = acc;
}

// ---------------- head: BN -> fc -> relu -> BN -> cls -> log_softmax ----------------
__global__ void head_kernel(const float* __restrict__ g, const float* __restrict__ hp,
                            const int* __restrict__ flag, void* __restrict__ out)
{
    __shared__ float gb[FHID];
    __shared__ float g2[FHID];
    __shared__ float lg[16];
    int gi = blockIdx.x, t = threadIdx.x;
    int isf32 = flag[0];
    const float rs = rsqrtf(1.0f + 1e-5f);
    gb[t] = g[gi*FHID + t] * (hp[17664 + t] * rs) + hp[17792 + t];
    __syncthreads();
    float acc = hp[17920 + t];
    for (int k = 0; k < FHID; k++) acc += gb[k] * hp[k*FHID + t];
    acc = fmaxf(acc, 0.f);
    g2[t] = acc * (hp[18048 + t] * rs) + hp[18176 + t];
    __syncthreads();
    if (t < NCLS){
        float l = hp[18304 + t];
        for (int k = 0; k < FHID; k++) l += g2[k] * hp[16384 + k*NCLS + t];
        lg[t] = l;
    }
    __syncthreads();
    if (t == 0){
        float mx = lg[0];
        for (int j = 1; j < NCLS; j++) mx = fmaxf(mx, lg[j]);
        float se = 0.f;
        for (int j = 0; j < NCLS; j++) se += __expf(lg[j] - mx);
        float lse = logf(se) + mx;
        if (isf32){
            float* o = (float*)out;
            for (int j = 0; j < NCLS; j++) o[gi*NCLS + j] = lg[j] - lse;
            if (gi == 0) o[NGRAPH*NCLS] = 0.f;
        } else {
            u16* o = (u16*)out;
            for (int j = 0; j < NCLS; j++) o[gi*NCLS + j] = f2bf(lg[j] - lse);
            if (gi == 0) o[NGRAPH*NCLS] = 0;
        }
    }
}

extern "C" void kernel_launch(void* const* d_in, const int* in_sizes, int n_in,
                              void* d_out, int out_size, void* d_ws, size_t ws_size,
                              hipStream_t stream)
{
    (void)in_sizes; (void)n_in; (void)out_size;
    const void* x         = d_in[0];
    const int* edge       = (const int*)d_in[1];
    const int* batch      = (const int*)d_in[2];

    char* ws = (char*)d_ws;
    size_t off = 0;
    auto alloc = [&](size_t bytes) -> char* {
        char* p = ws + off; off += (bytes + 255) & ~(size_t)255; return p;
    };
    int*   dflag   = (int*)  alloc(256);
    u16*   WtAll   = (u16*)  alloc((size_t)4*FHID*FHID*2);
    float* cvecAll = (float*)alloc((size_t)4*FHID*4);
    float* biasv   = (float*)alloc((size_t)4*FHID*4);
    float* headp   = (float*)alloc((size_t)19088*4);
    float* al      = (float*)alloc((size_t)NN*NHEAD*4);
    float* ar      = (float*)alloc((size_t)NN*NHEAD*4);
    int*   deg     = (int*)  alloc((size_t)NN*4);
    int*   rowst   = (int*)  alloc((size_t)(NN+1)*4);
    int*   cursor  = (int*)  alloc((size_t)NN*4);
    int*   bsum    = (int*)  alloc((size_t)256*4);
    float* g       = (float*)alloc((size_t)NGRAPH*FHID*4);
    int*   colbuf  = (int*)  alloc((size_t)EE*4);
    u16*   hA      = (u16*)  alloc((size_t)NN*FHID*2);
    u16* hX;   // doubles as hB (hX dead after first gemm consumes it)
    if (off + (size_t)NN*FHID*2 <= ws_size) hX = (u16*)alloc((size_t)NN*FHID*2);
    else                                    hX = (u16*)d_in[0];
    u16* hB = hX;

    const int* srcp = edge;
    const int* dstp = edge + EE;
    const int NB_N = (NN + 255)/256;
    const int NB_E = (EE + 255)/256;
    const int NB_X = (NN*FHID + 255)/256;

    detect_dtype<<<1, 256, 0, stream>>>((const u16*)x, dflag);
    prep_weights<<<4, 128, 0, stream>>>(d_in[5], d_in[6], d_in[3], d_in[4],
                                        d_in[9], d_in[7], d_in[8], d_in[12],
                                        dflag, WtAll, cvecAll, biasv);
    prep_head<<<1, 256, 0, stream>>>(d_in[15], d_in[16], d_in[13], d_in[14],
                                     d_in[17], d_in[18], d_in[19], d_in[20],
                                     d_in[10], d_in[11], dflag, headp);
    convert_x<<<NB_X, 256, 0, stream>>>(x, hX, dflag, NN*FHID);

    zero_i32<<<NB_N, 256, 0, stream>>>(deg, NN);
    count_deg<<<NB_E, 256, 0, stream>>>(dstp, deg);
    scan_block_sum<<<NB_N, 256, 0, stream>>>(deg, bsum, NN);
    scan_bsum_par<<<1, 256, 0, stream>>>(bsum, NB_N, rowst + NN);
    scan_final<<<NB_N, 256, 0, stream>>>(deg, bsum, rowst, NN);
    copy_i32<<<NB_N, 256, 0, stream>>>(rowst, cursor, NN);
    fill_csr<<<NB_E, 256, 0, stream>>>(srcp, dstp, cursor, colbuf);

    gemm128<<<(NN + 63)/64, 256, 0, stream>>>(hX, WtAll, cvecAll, hA, 1);

    for (int i = 0; i < 3; i++){
        gemm128<<<(NN + 63)/64, 256, 0, stream>>>(hA, WtAll + (i+1)*FHID*FHID,
                                                  cvecAll + (i+1)*FHID, hB, 0);
        node_alpha<<<(NN*NHEAD + 255)/256, 256, 0, stream>>>(hB, headp + 18320 + i*FHID,
                                                             headp + 18704 + i*FHID, al, ar);
        supergat_conv<<<(NN + 15)/16, 256, 0, stream>>>(hB, al, ar, rowst, colbuf,
                                                        biasv + (i+1)*FHID, hA);
    }

    pool_kernel<<<NGRAPH, 128, 0, stream>>>(hA, batch, g);
    head_kernel<<<NGRAPH, 128, 0, stream>>>(g, headp, dflag, d_out);
}

// Round 5
// 497.175 us; speedup vs baseline: 1.6889x; 1.1934x over previous
//
#include <hip/hip_runtime.h>

#define NN 50000
#define EE 800000
#define FHID 128
#define NHEAD 4
#define NGRAPH 512
#define NCLS 10

typedef unsigned short u16;
typedef unsigned int u32;
typedef __attribute__((ext_vector_type(8))) short bf16x8;
typedef __attribute__((ext_vector_type(4))) float f32x4;

__device__ __forceinline__ float bf2f(u16 u){
    union { u32 i; float f; } v; v.i = ((u32)u) << 16; return v.f;
}
__device__ __forceinline__ float bflo(u32 u){
    union { u32 i; float f; } v; v.i = u << 16; return v.f;
}
__device__ __forceinline__ float bfhi(u32 u){
    union { u32 i; float f; } v; v.i = u & 0xffff0000u; return v.f;
}
__device__ __forceinline__ u16 f2bf(float f){
    union { float f; u32 i; } v; v.f = f;
    u32 r = v.i + 0x7fffu + ((v.i >> 16) & 1u);
    return (u16)(r >> 16);
}
__device__ __forceinline__ u32 pack2(float a, float b){
    return ((u32)f2bf(b) << 16) | f2bf(a);
}
__device__ __forceinline__ float loadF(const void* p, int i, int isf32){
    return isf32 ? ((const float*)p)[i] : bf2f(((const u16*)p)[i]);
}
__device__ __forceinline__ void unpk8(uint4 v, float* f){
    f[0]=bflo(v.x); f[1]=bfhi(v.x);
    f[2]=bflo(v.y); f[3]=bfhi(v.y);
    f[4]=bflo(v.z); f[5]=bfhi(v.z);
    f[6]=bflo(v.w); f[7]=bfhi(v.w);
}

// ---------------- runtime input-dtype detection -------------------------------------
__global__ void detect_dtype(const u16* __restrict__ x, int* __restrict__ flag){
    __shared__ int cnt;
    if (threadIdx.x == 0) cnt = 0;
    __syncthreads();
    int ok = 0;
    for (int i = threadIdx.x; i < 1024; i += 256){
        u16 u = x[i];
        int e = (u >> 7) & 0xFF;
        if ((u & 0x7fff) == 0 || (e >= 0x70 && e <= 0x85)) ok++;
    }
    atomicAdd(&cnt, ok);
    __syncthreads();
    if (threadIdx.x == 0) flag[0] = (cnt < 900) ? 1 : 0;   // 1 = f32 inputs
}

// ---------------- weight prep v2: one block per (L,n), 128 threads over k -----------
__global__ void prep_weights(const void* __restrict__ w_feat, const void* __restrict__ b_feat,
                             const void* __restrict__ bn_feat_g, const void* __restrict__ bn_feat_b,
                             const void* __restrict__ w_gat, const void* __restrict__ bn_conv_g,
                             const void* __restrict__ bn_conv_b, const void* __restrict__ b_gat,
                             const int* __restrict__ flag,
                             u16* __restrict__ Wt, float* __restrict__ cvec,
                             float* __restrict__ biasv)
{
    __shared__ float red[128];
    int isf32 = flag[0];
    int L = blockIdx.x >> 7;          // 0..3
    int n = blockIdx.x & 127;         // output col
    int k = threadIdx.x;              // input row
    const float rs = rsqrtf(1.0f + 1e-5f);
    float wv, bg, bb;
    if (L == 0){
        wv = loadF(w_feat, k*FHID + n, isf32);
        bg = loadF(bn_feat_g, k, isf32);
        bb = loadF(bn_feat_b, k, isf32);
    } else {
        wv = loadF(w_gat, (L-1)*FHID*FHID + k*FHID + n, isf32);
        bg = loadF(bn_conv_g, (L-1)*FHID + k, isf32);
        bb = loadF(bn_conv_b, (L-1)*FHID + k, isf32);
    }
    Wt[L*FHID*FHID + n*FHID + k] = f2bf(bg * rs * wv);
    red[k] = bb * wv;
    __syncthreads();
    for (int o2 = 64; o2 > 0; o2 >>= 1){
        if (k < o2) red[k] += red[k + o2];
        __syncthreads();
    }
    if (k == 0){
        float c = red[0];
        if (L == 0) c += loadF(b_feat, n, isf32);
        cvec[L*FHID + n] = c;
        if (L > 0) biasv[L*FHID + n] = loadF(b_gat, (L-1)*FHID + n, isf32);
    }
}

// ---------------- head + attention params -> f32 workspace block --------------------
// hp layout: [0]=wfc 16384, [16384]=wcls 1280, [17664]=bnfcg, [17792]=bnfcb,
// [17920]=bfc, [18048]=bnhidg, [18176]=bnhidb, [18304]=bcls(10),
// [18320]=att_l 3*128, [18704]=att_r 3*128
__global__ void prep_head(const void* wfc, const void* bfc, const void* bnfg, const void* bnfb,
                          const void* bnhg, const void* bnhb, const void* wcls, const void* bcls,
                          const void* attl, const void* attr,
                          const int* __restrict__ flag, float* __restrict__ hp){
    int isf32 = flag[0];
    int gt = blockIdx.x*256 + threadIdx.x;   // 16 blocks x 256
    for (int i = gt; i < FHID*FHID; i += 16*256) hp[i] = loadF(wfc, i, isf32);
    if (gt < FHID*NCLS) hp[16384 + gt] = loadF(wcls, gt, isf32);
    if (gt >= 2048 && gt < 2048 + 3*FHID){
        int i = gt - 2048;
        hp[18320 + i] = loadF(attl, i, isf32);
        hp[18704 + i] = loadF(attr, i, isf32);
    }
    if (gt >= 2560 && gt < 2560 + FHID){
        int t = gt - 2560;
        hp[17664 + t] = loadF(bnfg, t, isf32);
        hp[17792 + t] = loadF(bnfb, t, isf32);
        hp[17920 + t] = loadF(bfc,  t, isf32);
        hp[18048 + t] = loadF(bnhg, t, isf32);
        hp[18176 + t] = loadF(bnhb, t, isf32);
    }
    if (gt >= 3072 && gt < 3072 + NCLS) hp[18304 + (gt - 3072)] = loadF(bcls, gt - 3072, isf32);
}

// ---------------- MFMA GEMM v2: 32 rows/wave, B-frag reuse, optional f32 input ------
__global__ __launch_bounds__(256) void gemm128(const void* __restrict__ A,
                                               const u16* __restrict__ Wt,
                                               const float* __restrict__ cvec,
                                               u16* __restrict__ out, int relu,
                                               int araw, const int* __restrict__ flag)
{
    int wave = threadIdx.x >> 6;
    int lane = threadIdx.x & 63;
    int m = lane & 15, quad = lane >> 4;
    int rowbase = blockIdx.x * 128 + wave * 32;
    bool f32in = araw && flag[0];
    const u16*  Au = (const u16*)A;
    const float* Af = (const float*)A;
    int r0 = rowbase + m, r1 = rowbase + 16 + m;
    bool v0 = r0 < NN, v1 = r1 < NN;
    f32x4 acc[2][8];
#pragma unroll
    for (int i = 0; i < 2; i++)
#pragma unroll
        for (int j = 0; j < 8; j++) acc[i][j] = (f32x4){0.f,0.f,0.f,0.f};
#pragma unroll
    for (int t = 0; t < 4; t++){
        bf16x8 a0 = {0,0,0,0,0,0,0,0}, a1 = {0,0,0,0,0,0,0,0};
        int kof = t*32 + quad*8;
        if (f32in){
            if (v0){
                const float* p = Af + (size_t)r0*FHID + kof;
                float4 u0 = *(const float4*)p, u1 = *(const float4*)(p+4);
                a0[0]=(short)f2bf(u0.x); a0[1]=(short)f2bf(u0.y);
                a0[2]=(short)f2bf(u0.z); a0[3]=(short)f2bf(u0.w);
                a0[4]=(short)f2bf(u1.x); a0[5]=(short)f2bf(u1.y);
                a0[6]=(short)f2bf(u1.z); a0[7]=(short)f2bf(u1.w);
            }
            if (v1){
                const float* p = Af + (size_t)r1*FHID + kof;
                float4 u0 = *(const float4*)p, u1 = *(const float4*)(p+4);
                a1[0]=(short)f2bf(u0.x); a1[1]=(short)f2bf(u0.y);
                a1[2]=(short)f2bf(u0.z); a1[3]=(short)f2bf(u0.w);
                a1[4]=(short)f2bf(u1.x); a1[5]=(short)f2bf(u1.y);
                a1[6]=(short)f2bf(u1.z); a1[7]=(short)f2bf(u1.w);
            }
        } else {
            if (v0) a0 = *(const bf16x8*)(Au + (size_t)r0*FHID + kof);
            if (v1) a1 = *(const bf16x8*)(Au + (size_t)r1*FHID + kof);
        }
#pragma unroll
        for (int ct = 0; ct < 8; ct++){
            bf16x8 bfrag = *(const bf16x8*)(Wt + (ct*16 + m)*FHID + kof);
            acc[0][ct] = __builtin_amdgcn_mfma_f32_16x16x32_bf16(a0, bfrag, acc[0][ct], 0, 0, 0);
            acc[1][ct] = __builtin_amdgcn_mfma_f32_16x16x32_bf16(a1, bfrag, acc[1][ct], 0, 0, 0);
        }
    }
#pragma unroll
    for (int tt = 0; tt < 2; tt++){
#pragma unroll
        for (int ct = 0; ct < 8; ct++){
            int col = ct*16 + m;
            float cb = cvec[col];
#pragma unroll
            for (int r = 0; r < 4; r++){
                int row = rowbase + tt*16 + quad*4 + r;
                if (row < NN){
                    float v = acc[tt][ct][r] + cb;
                    if (relu) v = fmaxf(v, 0.f);
                    out[(size_t)row*FHID + col] = f2bf(v);
                }
            }
        }
    }
}

// ---------------- per-node, per-head attention scalars ------------------------------
__global__ void node_alpha(const u16* __restrict__ hh, const float* __restrict__ attl,
                           const float* __restrict__ attr,
                           float* __restrict__ al, float* __restrict__ ar)
{
    int idx = blockIdx.x*blockDim.x + threadIdx.x;   // node*4 + head
    if (idx >= NN*NHEAD) return;
    int head = idx & 3;
    const u16* base = hh + (size_t)(idx >> 2)*FHID + head*32;
    float sl = 0.f, sr = 0.f;
#pragma unroll
    for (int v = 0; v < 4; v++){
        uint4 u = *(const uint4*)(base + v*8);
        float f[8]; unpk8(u, f);
#pragma unroll
        for (int j = 0; j < 8; j++){
            int c = head*32 + v*8 + j;
            sl += f[j] * attl[c];
            sr += f[j] * attr[c];
        }
    }
    al[idx] = sl; ar[idx] = sr;
}

// ---------------- CSR build ---------------------------------------------------------
__global__ void count_deg(const int* __restrict__ dst, int* __restrict__ deg){
    int e = blockIdx.x*256 + threadIdx.x;
    if (e < EE){
        u32 d = (u32)dst[e];
        if (d < NN) atomicAdd(&deg[d], 1);
    }
}
__global__ void scan_block_sum(const int* __restrict__ deg, int* __restrict__ bsum, int n){
    __shared__ int sm[256];
    int i = blockIdx.x*256 + threadIdx.x;
    sm[threadIdx.x] = (i < n) ? deg[i] : 0;
    __syncthreads();
    for (int off = 128; off > 0; off >>= 1){
        if (threadIdx.x < off) sm[threadIdx.x] += sm[threadIdx.x + off];
        __syncthreads();
    }
    if (threadIdx.x == 0) bsum[blockIdx.x] = sm[0];
}
__global__ void scan_bsum_par(int* bsum, int nb, int* total_out){
    __shared__ int sm[256];
    int t = threadIdx.x;
    int v = (t < nb) ? bsum[t] : 0;
    sm[t] = v;
    __syncthreads();
    for (int off = 1; off < 256; off <<= 1){
        int x = (t >= off) ? sm[t - off] : 0;
        __syncthreads();
        sm[t] += x;
        __syncthreads();
    }
    if (t < nb) bsum[t] = sm[t] - v;          // exclusive
    if (t == 255) *total_out = sm[255];       // grand total
}
// writes rowstart AND cursor (identical copies) — removes separate copy kernel
__global__ void scan_final(const int* __restrict__ deg, const int* __restrict__ bsum,
                           int* __restrict__ rowstart, int* __restrict__ cursor, int n){
    __shared__ int sm[256];
    int i = blockIdx.x*256 + threadIdx.x;
    int v = (i < n) ? deg[i] : 0;
    sm[threadIdx.x] = v;
    __syncthreads();
    for (int off = 1; off < 256; off <<= 1){
        int x = (threadIdx.x >= off) ? sm[threadIdx.x - off] : 0;
        __syncthreads();
        sm[threadIdx.x] += x;
        __syncthreads();
    }
    if (i < n){
        int rs = bsum[blockIdx.x] + sm[threadIdx.x] - v;   // exclusive
        rowstart[i] = rs;
        cursor[i] = rs;
    }
}
__global__ void fill_csr(const int* __restrict__ srcp, const int* __restrict__ dstp,
                         int* __restrict__ cursor, int* __restrict__ colb){
    int e = blockIdx.x*256 + threadIdx.x;
    if (e < EE){
        u32 d = (u32)dstp[e];
        if (d < NN){
            u32 pos = (u32)atomicAdd(&cursor[d], 1);
            if (pos < EE) colb[pos] = srcp[e];
        }
    }
}

// ---------------- SuperGAT conv v3: no-rescale softmax (bounded logits) -------------
// 4 nodes/wave, 16 lanes/node, 8 ch/lane; lane = group*16 + head*4 + q
__global__ __launch_bounds__(256) void supergat_conv(const u16* __restrict__ hh,
        const float* __restrict__ al, const float* __restrict__ ar,
        const int* __restrict__ rowstart, const int* __restrict__ colbuf,
        const float* __restrict__ bias, u16* __restrict__ hout)
{
    int wid  = (blockIdx.x*256 + threadIdx.x) >> 6;   // wave id
    int lane = threadIdx.x & 63;
    int group = lane >> 4;
    int gl    = lane & 15;
    int head  = gl >> 2;
    int q     = gl & 3;
    int node  = wid*4 + group;
    bool valid = node < NN;
    int chbase = head*32 + q*8;
    int snode = valid ? node : 0;

    uint4 hdv = *(const uint4*)(hh + (size_t)snode*FHID + chbase);
    float hd[8]; unpk8(hdv, hd);
    float arn = ar[snode*NHEAD + head];
    float aln = al[snode*NHEAD + head];

    // self loop (alpha bounded ~|5| structurally; clamp for exp safety)
    float d = hd[0]*hd[0]+hd[1]*hd[1]+hd[2]*hd[2]+hd[3]*hd[3]
            + hd[4]*hd[4]+hd[5]*hd[5]+hd[6]*hd[6]+hd[7]*hd[7];
    d += __shfl_xor(d, 1, 64);
    d += __shfl_xor(d, 2, 64);
    float a = (aln + arn) * (1.0f / (1.0f + __expf(-d)));
    a = (a > 0.0f) ? a : 0.2f*a;
    float p = __expf(fminf(a, 60.f));
    float s = p;
    float o[8];
#pragma unroll
    for (int i = 0; i < 8; i++) o[i] = p*hd[i];

    int e0 = valid ? rowstart[node]     : 0;
    int e1 = valid ? rowstart[node + 1] : 0;
    if (e0 < 0) e0 = 0;
    if (e1 > EE) e1 = EE;

    // software-pipelined edge loop
    int   src_nx = 0;
    uint4 hsv_nx = (uint4){0,0,0,0};
    float alf_nx = 0.f;
    if (e0 < e1){
        src_nx = colbuf[e0];
        if ((u32)src_nx >= NN) src_nx = 0;
        hsv_nx = *(const uint4*)(hh + (size_t)src_nx*FHID + chbase);
        alf_nx = al[src_nx*NHEAD + head];
    }
    for (int e = e0; e < e1; e++){
        uint4 hsv = hsv_nx;
        float alf = alf_nx;
        if (e + 1 < e1){
            int s2 = colbuf[e + 1];
            if ((u32)s2 >= NN) s2 = 0;
            src_nx = s2;
            hsv_nx = *(const uint4*)(hh + (size_t)s2*FHID + chbase);
            alf_nx = al[s2*NHEAD + head];
        }
        float hs[8]; unpk8(hsv, hs);
        float lg = hd[0]*hs[0]+hd[1]*hs[1]+hd[2]*hs[2]+hd[3]*hs[3]
                 + hd[4]*hs[4]+hd[5]*hs[5]+hd[6]*hs[6]+hd[7]*hs[7];
        lg += __shfl_xor(lg, 1, 64);
        lg += __shfl_xor(lg, 2, 64);
        float a2 = (alf + arn) * (1.0f / (1.0f + __expf(-lg)));
        a2 = (a2 > 0.0f) ? a2 : 0.2f*a2;
        float pe = __expf(fminf(a2, 60.f));
        s += pe;
#pragma unroll
        for (int i = 0; i < 8; i++) o[i] += pe*hs[i];
    }

    if (valid){
        float inv = 1.0f / (s + 1e-16f);
        uint4 w;
        w.x = pack2(fmaxf(o[0]*inv + bias[chbase+0], 0.f),
                    fmaxf(o[1]*inv + bias[chbase+1], 0.f));
        w.y = pack2(fmaxf(o[2]*inv + bias[chbase+2], 0.f),
                    fmaxf(o[3]*inv + bias[chbase+3], 0.f));
        w.z = pack2(fmaxf(o[4]*inv + bias[chbase+4], 0.f),
                    fmaxf(o[5]*inv + bias[chbase+5], 0.f));
        w.w = pack2(fmaxf(o[6]*inv + bias[chbase+6], 0.f),
                    fmaxf(o[7]*inv + bias[chbase+7], 0.f));
        *(uint4*)(hout + (size_t)node*FHID + chbase) = w;
    }
}

// ---------------- global add pool: one block per graph, binary search ---------------
__global__ void pool_kernel(const u16* __restrict__ h, const int* __restrict__ batch,
                            float* __restrict__ g)
{
    __shared__ int bounds[2];
    int b = blockIdx.x, t = threadIdx.x;
    if (t < 2){
        int target = b + t;
        int lo = 0, hi = NN;
        while (lo < hi){
            int mid = (lo + hi) >> 1;
            if (batch[mid] < target) lo = mid + 1; else hi = mid;
        }
        bounds[t] = lo;
    }
    __syncthreads();
    float acc = 0.f;
    for (int node = bounds[0]; node < bounds[1]; node++)
        acc += bf2f(h[(size_t)node*FHID + t]);
    g[b*FHID + t] = acc;
}

// ---------------- head: BN -> fc -> relu -> BN -> cls -> log_softmax ----------------
__global__ void head_kernel(const float* __restrict__ g, const float* __restrict__ hp,
                            const int* __restrict__ flag, void* __restrict__ out)
{
    __shared__ float gb[FHID];
    __shared__ float g2[FHID];
    __shared__ float lg[16];
    int gi = blockIdx.x, t = threadIdx.x;
    int isf32 = flag[0];
    const float rs = rsqrtf(1.0f + 1e-5f);
    gb[t] = g[gi*FHID + t] * (hp[17664 + t] * rs) + hp[17792 + t];
    __syncthreads();
    float acc = hp[17920 + t];
    for (int k = 0; k < FHID; k++) acc += gb[k] * hp[k*FHID + t];
    acc = fmaxf(acc, 0.f);
    g2[t] = acc * (hp[18048 + t] * rs) + hp[18176 + t];
    __syncthreads();
    if (t < NCLS){
        float l = hp[18304 + t];
        for (int k = 0; k < FHID; k++) l += g2[k] * hp[16384 + k*NCLS + t];
        lg[t] = l;
    }
    __syncthreads();
    if (t == 0){
        float mx = lg[0];
        for (int j = 1; j < NCLS; j++) mx = fmaxf(mx, lg[j]);
        float se = 0.f;
        for (int j = 0; j < NCLS; j++) se += __expf(lg[j] - mx);
        float lse = logf(se) + mx;
        if (isf32){
            float* o = (float*)out;
            for (int j = 0; j < NCLS; j++) o[gi*NCLS + j] = lg[j] - lse;
            if (gi == 0) o[NGRAPH*NCLS] = 0.f;
        } else {
            u16* o = (u16*)out;
            for (int j = 0; j < NCLS; j++) o[gi*NCLS + j] = f2bf(lg[j] - lse);
            if (gi == 0) o[NGRAPH*NCLS] = 0;
        }
    }
}

extern "C" void kernel_launch(void* const* d_in, const int* in_sizes, int n_in,
                              void* d_out, int out_size, void* d_ws, size_t ws_size,
                              hipStream_t stream)
{
    (void)in_sizes; (void)n_in; (void)out_size;
    const void* x         = d_in[0];
    const int* edge       = (const int*)d_in[1];
    const int* batch      = (const int*)d_in[2];

    char* ws = (char*)d_ws;
    size_t off = 0;
    auto alloc = [&](size_t bytes) -> char* {
        char* p = ws + off; off += (bytes + 255) & ~(size_t)255; return p;
    };
    int*   dflag   = (int*)  alloc(256);
    u16*   WtAll   = (u16*)  alloc((size_t)4*FHID*FHID*2);
    float* cvecAll = (float*)alloc((size_t)4*FHID*4);
    float* biasv   = (float*)alloc((size_t)4*FHID*4);
    float* headp   = (float*)alloc((size_t)19088*4);
    float* al      = (float*)alloc((size_t)NN*NHEAD*4);
    float* ar      = (float*)alloc((size_t)NN*NHEAD*4);
    int*   deg     = (int*)  alloc((size_t)NN*4);
    int*   rowst   = (int*)  alloc((size_t)(NN+1)*4);
    int*   cursor  = (int*)  alloc((size_t)NN*4);
    int*   bsum    = (int*)  alloc((size_t)256*4);
    float* g       = (float*)alloc((size_t)NGRAPH*FHID*4);
    int*   colbuf  = (int*)  alloc((size_t)EE*4);
    u16*   hA      = (u16*)  alloc((size_t)NN*FHID*2);
    u16*   hB      = (u16*)  alloc((size_t)NN*FHID*2);

    const int* srcp = edge;
    const int* dstp = edge + EE;
    const int NB_N = (NN + 255)/256;
    const int NB_E = (EE + 255)/256;

    detect_dtype<<<1, 256, 0, stream>>>((const u16*)x, dflag);
    prep_weights<<<512, 128, 0, stream>>>(d_in[5], d_in[6], d_in[3], d_in[4],
                                          d_in[9], d_in[7], d_in[8], d_in[12],
                                          dflag, WtAll, cvecAll, biasv);
    prep_head<<<16, 256, 0, stream>>>(d_in[15], d_in[16], d_in[13], d_in[14],
                                      d_in[17], d_in[18], d_in[19], d_in[20],
                                      d_in[10], d_in[11], dflag, headp);

    hipMemsetAsync(deg, 0, (size_t)NN*4, stream);
    count_deg<<<NB_E, 256, 0, stream>>>(dstp, deg);
    scan_block_sum<<<NB_N, 256, 0, stream>>>(deg, bsum, NN);
    scan_bsum_par<<<1, 256, 0, stream>>>(bsum, NB_N, rowst + NN);
    scan_final<<<NB_N, 256, 0, stream>>>(deg, bsum, rowst, cursor, NN);
    fill_csr<<<NB_E, 256, 0, stream>>>(srcp, dstp, cursor, colbuf);

    // feature layer: reads raw x (f32 or bf16 per flag), converts in-register
    gemm128<<<(NN + 127)/128, 256, 0, stream>>>(x, WtAll, cvecAll, hA, 1, 1, dflag);

    for (int i = 0; i < 3; i++){
        gemm128<<<(NN + 127)/128, 256, 0, stream>>>(hA, WtAll + (i+1)*FHID*FHID,
                                                    cvecAll + (i+1)*FHID, hB, 0, 0, dflag);
        node_alpha<<<(NN*NHEAD + 255)/256, 256, 0, stream>>>(hB, headp + 18320 + i*FHID,
                                                             headp + 18704 + i*FHID, al, ar);
        supergat_conv<<<(NN + 15)/16, 256, 0, stream>>>(hB, al, ar, rowst, colbuf,
                                                        biasv + (i+1)*FHID, hA);
    }

    pool_kernel<<<NGRAPH, 128, 0, stream>>>(hA, batch, g);
    head_kernel<<<NGRAPH, 128, 0, stream>>>(g, headp, dflag, d_out);
}

// Round 6
// 429.470 us; speedup vs baseline: 1.9552x; 1.1576x over previous
//
#include <hip/hip_runtime.h>

#define NN 50000
#define EE 800000
#define FHID 128
#define NHEAD 4
#define NGRAPH 512
#define NCLS 10
#define BK 256            // buckets (dst>>8)
#define BCH 4096          // edges per block in hist/bin kernels
#define NBLK_E 196        // ceil(EE/BCH)
#define NBUCK 196         // ceil(NN/256)
#define CAP 6144          // per-bucket LDS colstage capacity (mean 4082, ~32 sigma headroom)

typedef unsigned short u16;
typedef unsigned int u32;
typedef unsigned long long u64;
typedef __attribute__((ext_vector_type(8))) short bf16x8;
typedef __attribute__((ext_vector_type(4))) float f32x4;

__device__ __forceinline__ float bf2f(u16 u){
    union { u32 i; float f; } v; v.i = ((u32)u) << 16; return v.f;
}
__device__ __forceinline__ float bflo(u32 u){
    union { u32 i; float f; } v; v.i = u << 16; return v.f;
}
__device__ __forceinline__ float bfhi(u32 u){
    union { u32 i; float f; } v; v.i = u & 0xffff0000u; return v.f;
}
__device__ __forceinline__ u16 f2bf(float f){
    union { float f; u32 i; } v; v.f = f;
    u32 r = v.i + 0x7fffu + ((v.i >> 16) & 1u);
    return (u16)(r >> 16);
}
__device__ __forceinline__ u32 pack2(float a, float b){
    return ((u32)f2bf(b) << 16) | f2bf(a);
}
__device__ __forceinline__ float loadF(const void* p, int i, int isf32){
    return isf32 ? ((const float*)p)[i] : bf2f(((const u16*)p)[i]);
}
__device__ __forceinline__ void unpk8(uint4 v, float* f){
    f[0]=bflo(v.x); f[1]=bfhi(v.x);
    f[2]=bflo(v.y); f[3]=bfhi(v.y);
    f[4]=bflo(v.z); f[5]=bfhi(v.z);
    f[6]=bflo(v.w); f[7]=bfhi(v.w);
}

// ---------------- runtime input-dtype detection -------------------------------------
__global__ void detect_dtype(const u16* __restrict__ x, int* __restrict__ flag){
    __shared__ int cnt;
    if (threadIdx.x == 0) cnt = 0;
    __syncthreads();
    int ok = 0;
    for (int i = threadIdx.x; i < 1024; i += 256){
        u16 u = x[i];
        int e = (u >> 7) & 0xFF;
        if ((u & 0x7fff) == 0 || (e >= 0x70 && e <= 0x85)) ok++;
    }
    atomicAdd(&cnt, ok);
    __syncthreads();
    if (threadIdx.x == 0) flag[0] = (cnt < 900) ? 1 : 0;   // 1 = f32 inputs
}

// ---------------- weight prep: one block per (L,n), 128 threads over k --------------
__global__ void prep_weights(const void* __restrict__ w_feat, const void* __restrict__ b_feat,
                             const void* __restrict__ bn_feat_g, const void* __restrict__ bn_feat_b,
                             const void* __restrict__ w_gat, const void* __restrict__ bn_conv_g,
                             const void* __restrict__ bn_conv_b, const void* __restrict__ b_gat,
                             const int* __restrict__ flag,
                             u16* __restrict__ Wt, float* __restrict__ cvec,
                             float* __restrict__ biasv)
{
    __shared__ float red[128];
    int isf32 = flag[0];
    int L = blockIdx.x >> 7;
    int n = blockIdx.x & 127;
    int k = threadIdx.x;
    const float rs = rsqrtf(1.0f + 1e-5f);
    float wv, bg, bb;
    if (L == 0){
        wv = loadF(w_feat, k*FHID + n, isf32);
        bg = loadF(bn_feat_g, k, isf32);
        bb = loadF(bn_feat_b, k, isf32);
    } else {
        wv = loadF(w_gat, (L-1)*FHID*FHID + k*FHID + n, isf32);
        bg = loadF(bn_conv_g, (L-1)*FHID + k, isf32);
        bb = loadF(bn_conv_b, (L-1)*FHID + k, isf32);
    }
    Wt[L*FHID*FHID + n*FHID + k] = f2bf(bg * rs * wv);
    red[k] = bb * wv;
    __syncthreads();
    for (int o2 = 64; o2 > 0; o2 >>= 1){
        if (k < o2) red[k] += red[k + o2];
        __syncthreads();
    }
    if (k == 0){
        float c = red[0];
        if (L == 0) c += loadF(b_feat, n, isf32);
        cvec[L*FHID + n] = c;
        if (L > 0) biasv[L*FHID + n] = loadF(b_gat, (L-1)*FHID + n, isf32);
    }
}

// ---------------- head + attention params -> f32 workspace block --------------------
__global__ void prep_head(const void* wfc, const void* bfc, const void* bnfg, const void* bnfb,
                          const void* bnhg, const void* bnhb, const void* wcls, const void* bcls,
                          const void* attl, const void* attr,
                          const int* __restrict__ flag, float* __restrict__ hp){
    int isf32 = flag[0];
    int gt = blockIdx.x*256 + threadIdx.x;   // 16 blocks x 256
    for (int i = gt; i < FHID*FHID; i += 16*256) hp[i] = loadF(wfc, i, isf32);
    if (gt < FHID*NCLS) hp[16384 + gt] = loadF(wcls, gt, isf32);
    if (gt >= 2048 && gt < 2048 + 3*FHID){
        int i = gt - 2048;
        hp[18320 + i] = loadF(attl, i, isf32);
        hp[18704 + i] = loadF(attr, i, isf32);
    }
    if (gt >= 2560 && gt < 2560 + FHID){
        int t = gt - 2560;
        hp[17664 + t] = loadF(bnfg, t, isf32);
        hp[17792 + t] = loadF(bnfb, t, isf32);
        hp[17920 + t] = loadF(bfc,  t, isf32);
        hp[18048 + t] = loadF(bnhg, t, isf32);
        hp[18176 + t] = loadF(bnhb, t, isf32);
    }
    if (gt >= 3072 && gt < 3072 + NCLS) hp[18304 + (gt - 3072)] = loadF(bcls, gt - 3072, isf32);
}

// ---------------- MFMA GEMM v3: swapped operands -> lane holds 4 consecutive cols ---
// D = mfma(Wt_frag, node_frag): row(node) = rowbase + tt*16 + (lane&15),
// cols = ct*16 + quad*4 + r  -> dwordx2 stores.
__global__ __launch_bounds__(256) void gemm128(const void* __restrict__ A,
                                               const u16* __restrict__ Wt,
                                               const float* __restrict__ cvec,
                                               u16* __restrict__ out, int relu,
                                               int araw, const int* __restrict__ flag)
{
    int wave = threadIdx.x >> 6;
    int lane = threadIdx.x & 63;
    int m = lane & 15, quad = lane >> 4;
    int rowbase = blockIdx.x * 128 + wave * 32;
    bool f32in = araw && flag[0];
    const u16*  Au = (const u16*)A;
    const float* Af = (const float*)A;
    int r0 = rowbase + m, r1 = rowbase + 16 + m;
    bool v0 = r0 < NN, v1 = r1 < NN;
    f32x4 acc[2][8];
#pragma unroll
    for (int i = 0; i < 2; i++)
#pragma unroll
        for (int j = 0; j < 8; j++) acc[i][j] = (f32x4){0.f,0.f,0.f,0.f};
#pragma unroll
    for (int t = 0; t < 4; t++){
        bf16x8 a0 = {0,0,0,0,0,0,0,0}, a1 = {0,0,0,0,0,0,0,0};
        int kof = t*32 + quad*8;
        if (f32in){
            if (v0){
                const float* p = Af + (size_t)r0*FHID + kof;
                float4 u0 = *(const float4*)p, u1 = *(const float4*)(p+4);
                a0[0]=(short)f2bf(u0.x); a0[1]=(short)f2bf(u0.y);
                a0[2]=(short)f2bf(u0.z); a0[3]=(short)f2bf(u0.w);
                a0[4]=(short)f2bf(u1.x); a0[5]=(short)f2bf(u1.y);
                a0[6]=(short)f2bf(u1.z); a0[7]=(short)f2bf(u1.w);
            }
            if (v1){
                const float* p = Af + (size_t)r1*FHID + kof;
                float4 u0 = *(const float4*)p, u1 = *(const float4*)(p+4);
                a1[0]=(short)f2bf(u0.x); a1[1]=(short)f2bf(u0.y);
                a1[2]=(short)f2bf(u0.z); a1[3]=(short)f2bf(u0.w);
                a1[4]=(short)f2bf(u1.x); a1[5]=(short)f2bf(u1.y);
                a1[6]=(short)f2bf(u1.z); a1[7]=(short)f2bf(u1.w);
            }
        } else {
            if (v0) a0 = *(const bf16x8*)(Au + (size_t)r0*FHID + kof);
            if (v1) a1 = *(const bf16x8*)(Au + (size_t)r1*FHID + kof);
        }
#pragma unroll
        for (int ct = 0; ct < 8; ct++){
            bf16x8 wfrag = *(const bf16x8*)(Wt + (ct*16 + m)*FHID + kof);
            acc[0][ct] = __builtin_amdgcn_mfma_f32_16x16x32_bf16(wfrag, a0, acc[0][ct], 0, 0, 0);
            acc[1][ct] = __builtin_amdgcn_mfma_f32_16x16x32_bf16(wfrag, a1, acc[1][ct], 0, 0, 0);
        }
    }
#pragma unroll
    for (int tt = 0; tt < 2; tt++){
        int row = rowbase + tt*16 + m;
        if (row < NN){
#pragma unroll
            for (int ct = 0; ct < 8; ct++){
                int cb = ct*16 + quad*4;
                float4 cv = *(const float4*)(cvec + cb);
                float w0 = acc[tt][ct][0] + cv.x;
                float w1 = acc[tt][ct][1] + cv.y;
                float w2 = acc[tt][ct][2] + cv.z;
                float w3 = acc[tt][ct][3] + cv.w;
                if (relu){
                    w0 = fmaxf(w0, 0.f); w1 = fmaxf(w1, 0.f);
                    w2 = fmaxf(w2, 0.f); w3 = fmaxf(w3, 0.f);
                }
                uint2 st; st.x = pack2(w0, w1); st.y = pack2(w2, w3);
                *(uint2*)(out + (size_t)row*FHID + cb) = st;
            }
        }
    }
}

// ---------------- per-node, per-head attention scalars ------------------------------
__global__ void node_alpha(const u16* __restrict__ hh, const float* __restrict__ attl,
                           const float* __restrict__ attr,
                           float* __restrict__ al, float* __restrict__ ar)
{
    int idx = blockIdx.x*blockDim.x + threadIdx.x;   // node*4 + head
    if (idx >= NN*NHEAD) return;
    int head = idx & 3;
    const u16* base = hh + (size_t)(idx >> 2)*FHID + head*32;
    float sl = 0.f, sr = 0.f;
#pragma unroll
    for (int v = 0; v < 4; v++){
        uint4 u = *(const uint4*)(base + v*8);
        float f[8]; unpk8(u, f);
#pragma unroll
        for (int j = 0; j < 8; j++){
            int c = head*32 + v*8 + j;
            sl += f[j] * attl[c];
            sr += f[j] * attr[c];
        }
    }
    al[idx] = sl; ar[idx] = sr;
}

// ---------------- bucketed CSR build -------------------------------------------------
// bucket(d) = d >> 8 (256 nodes each). Coalesced writes throughout.
__global__ __launch_bounds__(256) void bucket_hist(const int* __restrict__ dst,
                                                   int* __restrict__ gcnt){
    __shared__ int h[BK];
    int t = threadIdx.x;
    h[t] = 0;
    __syncthreads();
    int base = blockIdx.x * BCH;
#pragma unroll
    for (int k = 0; k < 16; k++){
        int e = base + k*256 + t;
        if (e < EE){
            u32 d = (u32)dst[e];
            if (d < NN) atomicAdd(&h[d >> 8], 1);
        }
    }
    __syncthreads();
    if (h[t]) atomicAdd(&gcnt[t], h[t]);
}

__global__ void bucket_scan(const int* __restrict__ gcnt, int* __restrict__ gbase,
                            int* __restrict__ gcur, int* __restrict__ rowst){
    __shared__ int sm[BK];
    int t = threadIdx.x;
    int v = gcnt[t];
    sm[t] = v;
    __syncthreads();
    for (int off = 1; off < BK; off <<= 1){
        int x = (t >= off) ? sm[t - off] : 0;
        __syncthreads();
        sm[t] += x;
        __syncthreads();
    }
    gbase[t] = sm[t] - v;
    gcur[t]  = sm[t] - v;
    if (t == BK - 1) rowst[NN] = sm[t];   // total edge count
}

__global__ __launch_bounds__(256) void bin_edges(const int* __restrict__ srcp,
        const int* __restrict__ dstp, int* __restrict__ gcur, u64* __restrict__ binned)
{
    __shared__ int h[BK], lb[BK], gb[BK], cur[BK];
    __shared__ u64 stage[BCH];
    int t = threadIdx.x;
    h[t] = 0;
    __syncthreads();
    int base = blockIdx.x * BCH;
    int sv[16], dv[16];
#pragma unroll
    for (int k = 0; k < 16; k++){
        int e = base + k*256 + t;
        int d = -1, s = 0;
        if (e < EE){
            d = dstp[e]; s = srcp[e];
            if ((u32)d >= NN) d = -1;
        }
        sv[k] = s; dv[k] = d;
        if (d >= 0) atomicAdd(&h[d >> 8], 1);
    }
    __syncthreads();
    lb[t] = h[t];
    __syncthreads();
    for (int off = 1; off < BK; off <<= 1){
        int x = (t >= off) ? lb[t - off] : 0;
        __syncthreads();
        lb[t] += x;
        __syncthreads();
    }
    int excl = lb[t] - h[t];
    int tot  = lb[BK-1];
    __syncthreads();
    lb[t] = excl;
    gb[t] = h[t] ? atomicAdd(&gcur[t], h[t]) : 0;
    cur[t] = 0;
    __syncthreads();
#pragma unroll
    for (int k = 0; k < 16; k++){
        int d = dv[k];
        if (d >= 0){
            int b = d >> 8;
            int p = lb[b] + atomicAdd(&cur[b], 1);
            stage[p] = ((u64)(u32)d << 32) | (u32)sv[k];
        }
    }
    __syncthreads();
    for (int i = t; i < tot; i += 256){
        u64 pr = stage[i];
        int b = (int)(pr >> 40);             // d >> 8
        binned[gb[b] + (i - lb[b])] = pr;
    }
}

__global__ __launch_bounds__(256) void build_csr(const u64* __restrict__ binned,
        const int* __restrict__ gbase, const int* __restrict__ gcnt,
        int* __restrict__ rowst, int* __restrict__ colbuf)
{
    __shared__ int deg[BK], ls[BK], cur[BK];
    __shared__ int colstage[CAP];
    int b = blockIdx.x, t = threadIdx.x;
    int gb = gbase[b], cnt = gcnt[b];
    deg[t] = 0;
    __syncthreads();
    for (int i = t; i < cnt; i += 256){
        int d = (int)(binned[gb + i] >> 32);
        atomicAdd(&deg[d & 255], 1);
    }
    __syncthreads();
    ls[t] = deg[t];
    __syncthreads();
    for (int off = 1; off < BK; off <<= 1){
        int x = (t >= off) ? ls[t - off] : 0;
        __syncthreads();
        ls[t] += x;
        __syncthreads();
    }
    int excl = ls[t] - deg[t];
    int node = b*256 + t;
    if (node < NN) rowst[node] = gb + excl;
    cur[t] = excl;
    __syncthreads();
    for (int i = t; i < cnt; i += 256){
        u64 pr = binned[gb + i];
        int d = (int)(pr >> 32) & 255;
        int s = (int)(u32)pr;
        int p = atomicAdd(&cur[d], 1);
        if (p < CAP) colstage[p] = s;
        else colbuf[gb + p] = s;             // overflow fallback (statistically never)
    }
    __syncthreads();
    int mm = min(cnt, CAP);
    for (int i = t; i < mm; i += 256) colbuf[gb + i] = colstage[i];
}

// ---------------- SuperGAT conv v4: 2-wide edge unroll ------------------------------
// 4 nodes/wave, 16 lanes/node, 8 ch/lane; lane = group*16 + head*4 + q
__global__ __launch_bounds__(256) void supergat_conv(const u16* __restrict__ hh,
        const float* __restrict__ al, const float* __restrict__ ar,
        const int* __restrict__ rowstart, const int* __restrict__ colbuf,
        const float* __restrict__ bias, u16* __restrict__ hout)
{
    int wid  = (blockIdx.x*256 + threadIdx.x) >> 6;
    int lane = threadIdx.x & 63;
    int group = lane >> 4;
    int gl    = lane & 15;
    int head  = gl >> 2;
    int q     = gl & 3;
    int node  = wid*4 + group;
    bool valid = node < NN;
    int chbase = head*32 + q*8;
    int snode = valid ? node : 0;

    uint4 hdv = *(const uint4*)(hh + (size_t)snode*FHID + chbase);
    float hd[8]; unpk8(hdv, hd);
    float arn = ar[snode*NHEAD + head];
    float aln = al[snode*NHEAD + head];

    float d = hd[0]*hd[0]+hd[1]*hd[1]+hd[2]*hd[2]+hd[3]*hd[3]
            + hd[4]*hd[4]+hd[5]*hd[5]+hd[6]*hd[6]+hd[7]*hd[7];
    d += __shfl_xor(d, 1, 64);
    d += __shfl_xor(d, 2, 64);
    float a = (aln + arn) * (1.0f / (1.0f + __expf(-d)));
    a = (a > 0.0f) ? a : 0.2f*a;
    float p = __expf(fminf(a, 60.f));
    float s = p;
    float o[8];
#pragma unroll
    for (int i = 0; i < 8; i++) o[i] = p*hd[i];

    int e0 = valid ? rowstart[node]     : 0;
    int e1 = valid ? rowstart[node + 1] : 0;
    if (e0 < 0) e0 = 0;
    if (e1 > EE) e1 = EE;

    int e = e0;
    for (; e + 1 < e1; e += 2){
        int s1 = colbuf[e], s2 = colbuf[e + 1];
        if ((u32)s1 >= NN) s1 = 0;
        if ((u32)s2 >= NN) s2 = 0;
        uint4 x1 = *(const uint4*)(hh + (size_t)s1*FHID + chbase);
        uint4 x2 = *(const uint4*)(hh + (size_t)s2*FHID + chbase);
        float af1 = al[s1*NHEAD + head];
        float af2 = al[s2*NHEAD + head];
        float hs[8];
        unpk8(x1, hs);
        float lg = hd[0]*hs[0]+hd[1]*hs[1]+hd[2]*hs[2]+hd[3]*hs[3]
                 + hd[4]*hs[4]+hd[5]*hs[5]+hd[6]*hs[6]+hd[7]*hs[7];
        lg += __shfl_xor(lg, 1, 64);
        lg += __shfl_xor(lg, 2, 64);
        float a2 = (af1 + arn) * (1.0f / (1.0f + __expf(-lg)));
        a2 = (a2 > 0.0f) ? a2 : 0.2f*a2;
        float pe = __expf(fminf(a2, 60.f));
        s += pe;
#pragma unroll
        for (int i = 0; i < 8; i++) o[i] += pe*hs[i];
        unpk8(x2, hs);
        lg = hd[0]*hs[0]+hd[1]*hs[1]+hd[2]*hs[2]+hd[3]*hs[3]
           + hd[4]*hs[4]+hd[5]*hs[5]+hd[6]*hs[6]+hd[7]*hs[7];
        lg += __shfl_xor(lg, 1, 64);
        lg += __shfl_xor(lg, 2, 64);
        a2 = (af2 + arn) * (1.0f / (1.0f + __expf(-lg)));
        a2 = (a2 > 0.0f) ? a2 : 0.2f*a2;
        pe = __expf(fminf(a2, 60.f));
        s += pe;
#pragma unroll
        for (int i = 0; i < 8; i++) o[i] += pe*hs[i];
    }
    if (e < e1){
        int s1 = colbuf[e];
        if ((u32)s1 >= NN) s1 = 0;
        uint4 x1 = *(const uint4*)(hh + (size_t)s1*FHID + chbase);
        float af1 = al[s1*NHEAD + head];
        float hs[8]; unpk8(x1, hs);
        float lg = hd[0]*hs[0]+hd[1]*hs[1]+hd[2]*hs[2]+hd[3]*hs[3]
                 + hd[4]*hs[4]+hd[5]*hs[5]+hd[6]*hs[6]+hd[7]*hs[7];
        lg += __shfl_xor(lg, 1, 64);
        lg += __shfl_xor(lg, 2, 64);
        float a2 = (af1 + arn) * (1.0f / (1.0f + __expf(-lg)));
        a2 = (a2 > 0.0f) ? a2 : 0.2f*a2;
        float pe = __expf(fminf(a2, 60.f));
        s += pe;
#pragma unroll
        for (int i = 0; i < 8; i++) o[i] += pe*hs[i];
    }

    if (valid){
        float inv = 1.0f / (s + 1e-16f);
        uint4 w;
        w.x = pack2(fmaxf(o[0]*inv + bias[chbase+0], 0.f),
                    fmaxf(o[1]*inv + bias[chbase+1], 0.f));
        w.y = pack2(fmaxf(o[2]*inv + bias[chbase+2], 0.f),
                    fmaxf(o[3]*inv + bias[chbase+3], 0.f));
        w.z = pack2(fmaxf(o[4]*inv + bias[chbase+4], 0.f),
                    fmaxf(o[5]*inv + bias[chbase+5], 0.f));
        w.w = pack2(fmaxf(o[6]*inv + bias[chbase+6], 0.f),
                    fmaxf(o[7]*inv + bias[chbase+7], 0.f));
        *(uint4*)(hout + (size_t)node*FHID + chbase) = w;
    }
}

// ---------------- global add pool: one block per graph, binary search ---------------
__global__ void pool_kernel(const u16* __restrict__ h, const int* __restrict__ batch,
                            float* __restrict__ g)
{
    __shared__ int bounds[2];
    int b = blockIdx.x, t = threadIdx.x;
    if (t < 2){
        int target = b + t;
        int lo = 0, hi = NN;
        while (lo < hi){
            int mid = (lo + hi) >> 1;
            if (batch[mid] < target) lo = mid + 1; else hi = mid;
        }
        bounds[t] = lo;
    }
    __syncthreads();
    float acc = 0.f;
    for (int node = bounds[0]; node < bounds[1]; node++)
        acc += bf2f(h[(size_t)node*FHID + t]);
    g[b*FHID + t] = acc;
}

// ---------------- head: BN -> fc -> relu -> BN -> cls -> log_softmax ----------------
__global__ void head_kernel(const float* __restrict__ g, const float* __restrict__ hp,
                            const int* __restrict__ flag, void* __restrict__ out)
{
    __shared__ float gb[FHID];
    __shared__ float g2[FHID];
    __shared__ float lg[16];
    int gi = blockIdx.x, t = threadIdx.x;
    int isf32 = flag[0];
    const float rs = rsqrtf(1.0f + 1e-5f);
    gb[t] = g[gi*FHID + t] * (hp[17664 + t] * rs) + hp[17792 + t];
    __syncthreads();
    float acc = hp[17920 + t];
    for (int k = 0; k < FHID; k++) acc += gb[k] * hp[k*FHID + t];
    acc = fmaxf(acc, 0.f);
    g2[t] = acc * (hp[18048 + t] * rs) + hp[18176 + t];
    __syncthreads();
    if (t < NCLS){
        float l = hp[18304 + t];
        for (int k = 0; k < FHID; k++) l += g2[k] * hp[16384 + k*NCLS + t];
        lg[t] = l;
    }
    __syncthreads();
    if (t == 0){
        float mx = lg[0];
        for (int j = 1; j < NCLS; j++) mx = fmaxf(mx, lg[j]);
        float se = 0.f;
        for (int j = 0; j < NCLS; j++) se += __expf(lg[j] - mx);
        float lse = logf(se) + mx;
        if (isf32){
            float* o = (float*)out;
            for (int j = 0; j < NCLS; j++) o[gi*NCLS + j] = lg[j] - lse;
            if (gi == 0) o[NGRAPH*NCLS] = 0.f;
        } else {
            u16* o = (u16*)out;
            for (int j = 0; j < NCLS; j++) o[gi*NCLS + j] = f2bf(lg[j] - lse);
            if (gi == 0) o[NGRAPH*NCLS] = 0;
        }
    }
}

extern "C" void kernel_launch(void* const* d_in, const int* in_sizes, int n_in,
                              void* d_out, int out_size, void* d_ws, size_t ws_size,
                              hipStream_t stream)
{
    (void)in_sizes; (void)n_in; (void)out_size; (void)ws_size;
    const void* x         = d_in[0];
    const int* edge       = (const int*)d_in[1];
    const int* batch      = (const int*)d_in[2];

    char* ws = (char*)d_ws;
    size_t off = 0;
    auto alloc = [&](size_t bytes) -> char* {
        char* p = ws + off; off += (bytes + 255) & ~(size_t)255; return p;
    };
    int*   dflag   = (int*)  alloc(256);
    u16*   WtAll   = (u16*)  alloc((size_t)4*FHID*FHID*2);
    float* cvecAll = (float*)alloc((size_t)4*FHID*4);
    float* biasv   = (float*)alloc((size_t)4*FHID*4);
    float* headp   = (float*)alloc((size_t)19088*4);
    float* al      = (float*)alloc((size_t)NN*NHEAD*4);
    float* ar      = (float*)alloc((size_t)NN*NHEAD*4);
    int*   rowst   = (int*)  alloc((size_t)(NN+1)*4);
    int*   gcnt    = (int*)  alloc((size_t)BK*4);
    int*   gbase   = (int*)  alloc((size_t)BK*4);
    int*   gcur    = (int*)  alloc((size_t)BK*4);
    float* g       = (float*)alloc((size_t)NGRAPH*FHID*4);
    int*   colbuf  = (int*)  alloc((size_t)EE*4);
    u16*   hA      = (u16*)  alloc((size_t)NN*FHID*2);
    u16*   hB      = (u16*)  alloc((size_t)NN*FHID*2);
    // binned (6.4 MB) aliases hB (12.8 MB): hB is first written by the layer-1 gemm,
    // strictly after build_csr completes (stream-ordered).
    u64*   binned  = (u64*)hB;

    const int* srcp = edge;
    const int* dstp = edge + EE;

    detect_dtype<<<1, 256, 0, stream>>>((const u16*)x, dflag);
    prep_weights<<<512, 128, 0, stream>>>(d_in[5], d_in[6], d_in[3], d_in[4],
                                          d_in[9], d_in[7], d_in[8], d_in[12],
                                          dflag, WtAll, cvecAll, biasv);
    prep_head<<<16, 256, 0, stream>>>(d_in[15], d_in[16], d_in[13], d_in[14],
                                      d_in[17], d_in[18], d_in[19], d_in[20],
                                      d_in[10], d_in[11], dflag, headp);

    hipMemsetAsync(gcnt, 0, (size_t)BK*4, stream);
    bucket_hist<<<NBLK_E, 256, 0, stream>>>(dstp, gcnt);
    bucket_scan<<<1, 256, 0, stream>>>(gcnt, gbase, gcur, rowst);
    bin_edges<<<NBLK_E, 256, 0, stream>>>(srcp, dstp, gcur, binned);
    build_csr<<<NBUCK, 256, 0, stream>>>(binned, gbase, gcnt, rowst, colbuf);

    // feature layer: reads raw x (f32 or bf16 per flag), converts in-register
    gemm128<<<(NN + 127)/128, 256, 0, stream>>>(x, WtAll, cvecAll, hA, 1, 1, dflag);

    for (int i = 0; i < 3; i++){
        gemm128<<<(NN + 127)/128, 256, 0, stream>>>(hA, WtAll + (i+1)*FHID*FHID,
                                                    cvecAll + (i+1)*FHID, hB, 0, 0, dflag);
        node_alpha<<<(NN*NHEAD + 255)/256, 256, 0, stream>>>(hB, headp + 18320 + i*FHID,
                                                             headp + 18704 + i*FHID, al, ar);
        supergat_conv<<<(NN + 15)/16, 256, 0, stream>>>(hB, al, ar, rowst, colbuf,
                                                        biasv + (i+1)*FHID, hA);
    }

    pool_kernel<<<NGRAPH, 128, 0, stream>>>(hA, batch, g);
    head_kernel<<<NGRAPH, 128, 0, stream>>>(g, headp, dflag, d_out);
}